// Round 5
// baseline (422.788 us; speedup 1.0000x reference)
//
#include <hip/hip_runtime.h>

// ---------------------------------------------------------------------------
// Transformer block for MI355X (gfx950).  R5: attention softmax de-VALU'd —
//   S^T = K·Q^T (swapped MFMA operands) puts each lane's 16 scores on ONE
//   Q row: row max/sum = in-lane trees + 2 shfl_xor (no DPP chains), and the
//   S^T C-layout IS the A-layout of mfma_16x16x16bf16_1k -> P feeds PV
//   directly from registers (Ps LDS roundtrip eliminated).  perm-packed bf16.
//   1024 blocks longest-first (4 blocks/CU).  GEMMs unchanged from R4.
// ---------------------------------------------------------------------------

typedef short  bf16x8 __attribute__((ext_vector_type(8)));
typedef short  bf16x4 __attribute__((ext_vector_type(4)));
typedef float  fx4    __attribute__((ext_vector_type(4)));
typedef int    ix2    __attribute__((ext_vector_type(2)));

#define DEV static __device__ __forceinline__

DEV short f2bf(float f) {                 // round-to-nearest-even fp32 -> bf16
    unsigned u = __builtin_bit_cast(unsigned, f);
    u += 0x7fffu + ((u >> 16) & 1u);
    return (short)(u >> 16);
}

// address-space casts for global_load_lds
#define AS1(p) ((__attribute__((address_space(1))) void*)(p))
#define AS3(p) ((__attribute__((address_space(3))) void*)(p))

// ---------------------------------------------------------------------------
// LayerNorm: fp32 [4096][1024] -> bf16 [4096][1024].  One block (256t) / row.
// ---------------------------------------------------------------------------
__global__ __launch_bounds__(256) void ln_kernel(const float* __restrict__ x,
                                                 const float* __restrict__ w,
                                                 const float* __restrict__ b,
                                                 short* __restrict__ out)
{
    int row = blockIdx.x;
    int tid = threadIdx.x;
    const float4 v = *(const float4*)(x + (size_t)row * 1024 + tid * 4);
    float s = v.x + v.y + v.z + v.w;
    float q = v.x * v.x + v.y * v.y + v.z * v.z + v.w * v.w;
#pragma unroll
    for (int off = 32; off > 0; off >>= 1) {
        s += __shfl_down(s, off);
        q += __shfl_down(q, off);
    }
    __shared__ float ls[4], lq[4];
    if ((tid & 63) == 0) { ls[tid >> 6] = s; lq[tid >> 6] = q; }
    __syncthreads();
    float S  = ls[0] + ls[1] + ls[2] + ls[3];
    float Q  = lq[0] + lq[1] + lq[2] + lq[3];
    float mu  = S * (1.0f / 1024.0f);
    float var = Q * (1.0f / 1024.0f) - mu * mu;
    float inv = rsqrtf(var + 1e-5f);
    float4 wv = *(const float4*)(w + tid * 4);
    float4 bv = *(const float4*)(b + tid * 4);
    bf16x4 o;
    o[0] = f2bf((v.x - mu) * inv * wv.x + bv.x);
    o[1] = f2bf((v.y - mu) * inv * wv.y + bv.y);
    o[2] = f2bf((v.z - mu) * inv * wv.z + bv.z);
    o[3] = f2bf((v.w - mu) * inv * wv.w + bv.w);
    *(bf16x4*)(out + (size_t)row * 1024 + tid * 4) = o;
}

// ---------------------------------------------------------------------------
// Weight transpose+cast: fp32 [R][C] -> bf16 [C][R].  32x32 tiles, block 32x8.
// ---------------------------------------------------------------------------
__global__ void transpose_f32_bf16(const float* __restrict__ in,
                                   short* __restrict__ out, int R, int C)
{
    __shared__ float tile[32][33];
    int c0 = blockIdx.x * 32, r0 = blockIdx.y * 32;
    int tx = threadIdx.x, ty = threadIdx.y;
#pragma unroll
    for (int dy = 0; dy < 32; dy += 8)
        tile[ty + dy][tx] = in[(size_t)(r0 + ty + dy) * C + c0 + tx];
    __syncthreads();
#pragma unroll
    for (int dy = 0; dy < 32; dy += 8)
        out[(size_t)(c0 + ty + dy) * R + r0 + tx] = f2bf(tile[tx][ty + dy]);
}

// ---------------------------------------------------------------------------
// Extract V^T per (b,h): qkv bf16 [4096][3072] cols[2048+h*64 .. +64)
//   -> vt [b][h][64][2048] (d-major, t contiguous) for PV's B-operand.
// ---------------------------------------------------------------------------
__global__ void vt_extract(const short* __restrict__ qkv, short* __restrict__ vt)
{
    __shared__ short tile[32][33];
    int t0 = blockIdx.x * 32, d0 = blockIdx.y * 32;
    int bh = blockIdx.z;                       // b*16 + h
    int tx = threadIdx.x, ty = threadIdx.y;
    size_t inbase  = (size_t)(bh >> 4) * 2048 * 3072 + 2048 + (bh & 15) * 64;
    size_t outbase = (size_t)bh * 64 * 2048;
#pragma unroll
    for (int dy = 0; dy < 32; dy += 8)
        tile[ty + dy][tx] = qkv[inbase + (size_t)(t0 + ty + dy) * 3072 + d0 + tx];
    __syncthreads();
#pragma unroll
    for (int dy = 0; dy < 32; dy += 8)
        vt[outbase + (size_t)(d0 + ty + dy) * 2048 + t0 + tx] = tile[tx][ty + dy];
}

// ---------------------------------------------------------------------------
// GEMM  C[M][N] = epi( A[M][K](bf16) * Bt[N][K](bf16)^T )
// 128xBN tile / 256 threads, BK=32, global_load_lds(16B), double-buffered
// LDS with ONE barrier per k-iter.  4-granule XOR swizzle on LDS tiles.
// Split-K: SK = gridDim.z; PARTIAL mode writes fp32 partials.
// ---------------------------------------------------------------------------
template <int BN, bool BIAS, bool GELU, bool RESID, bool OUT_BF16, bool PARTIAL>
__global__ __launch_bounds__(256) void gemm_bt(const short* __restrict__ A,
                                               const short* __restrict__ Bt,
                                               void* __restrict__ Cout,
                                               void* __restrict__ Cout2,
                                               const float* __restrict__ bias,
                                               const float* __restrict__ resid,
                                               int M, int N, int K)
{
    constexpr int NJ = BN / 32;                    // 16-col tiles per wave
    __shared__ short As[2][128 * 32];
    __shared__ short Bs[2][BN * 32];
    int tid  = threadIdx.x;
    int lane = tid & 63, wv = tid >> 6;
    int quad = lane >> 4, l15 = lane & 15;
    int m0 = blockIdx.y * 128, n0 = blockIdx.x * BN;
    int SK   = gridDim.z;
    int kbeg = blockIdx.z * (K / SK);
    int NK   = (K / SK) / 32;
    int wr = (wv >> 1) * 64, wc = (wv & 1) * (BN / 2);
    fx4 acc[4][NJ] = {};
    int srow = lane >> 2;                          // staging: 16 rows / chunk
    int scol = ((lane & 3) ^ (srow & 3)) * 8;      // XOR-swizzled src granule
    int rg   = (quad ^ (l15 & 3)) * 8;             // swizzled fragment offset
    const short* Ab = A  + (size_t)m0 * K;
    const short* Bb = Bt + (size_t)n0 * K;

    auto stage = [&](int buf, int k0) {
#pragma unroll
        for (int c = wv; c < 8; c += 4) {
            int row = c * 16 + srow;
            __builtin_amdgcn_global_load_lds(AS1(Ab + (size_t)row * K + k0 + scol),
                                             AS3(&As[buf][c * 512]), 16, 0, 0);
        }
#pragma unroll
        for (int c = wv; c < BN / 16; c += 4) {
            int row = c * 16 + srow;
            __builtin_amdgcn_global_load_lds(AS1(Bb + (size_t)row * K + k0 + scol),
                                             AS3(&Bs[buf][c * 512]), 16, 0, 0);
        }
    };

    stage(0, kbeg);
    __syncthreads();
    for (int kt = 0; kt < NK; ++kt) {
        int cur = kt & 1;
        if (kt + 1 < NK) stage(cur ^ 1, kbeg + (kt + 1) * 32);
        bf16x8 af[4], bfr[NJ];
#pragma unroll
        for (int i = 0; i < 4; ++i)
            af[i] = *(const bf16x8*)&As[cur][(wr + i * 16 + l15) * 32 + rg];
#pragma unroll
        for (int j = 0; j < NJ; ++j)
            bfr[j] = *(const bf16x8*)&Bs[cur][(wc + j * 16 + l15) * 32 + rg];
#pragma unroll
        for (int i = 0; i < 4; ++i)
#pragma unroll
            for (int j = 0; j < NJ; ++j)
                acc[i][j] = __builtin_amdgcn_mfma_f32_16x16x32_bf16(af[i], bfr[j], acc[i][j], 0, 0, 0);
        __syncthreads();
    }

    if constexpr (PARTIAL) {
        float* P = blockIdx.z ? (float*)Cout2 : (float*)Cout;
#pragma unroll
        for (int i = 0; i < 4; ++i)
#pragma unroll
            for (int j = 0; j < NJ; ++j)
#pragma unroll
                for (int r = 0; r < 4; ++r) {
                    int row = m0 + wr + i * 16 + quad * 4 + r;
                    int col = n0 + wc + j * 16 + l15;
                    P[(size_t)row * N + col] = acc[i][j][r];
                }
    } else {
#pragma unroll
        for (int i = 0; i < 4; ++i)
#pragma unroll
            for (int j = 0; j < NJ; ++j)
#pragma unroll
                for (int r = 0; r < 4; ++r) {
                    int row = m0 + wr + i * 16 + quad * 4 + r;
                    int col = n0 + wc + j * 16 + l15;
                    float v = acc[i][j][r];
                    if constexpr (BIAS)  v += bias[col];
                    if constexpr (GELU)  v = 0.5f * v * (1.0f + erff(v * 0.70710678118654752f));
                    if constexpr (RESID) v += resid[(size_t)row * N + col];
                    if constexpr (OUT_BF16) ((short*)Cout)[(size_t)row * N + col] = f2bf(v);
                    else                    ((float*)Cout)[(size_t)row * N + col] = v;
                }
    }
}

// ---------------------------------------------------------------------------
// Split-K reduce: out = p0 + p1 + resid (+ bias).  float4 vectorized.
// ---------------------------------------------------------------------------
template <bool BIAS>
__global__ __launch_bounds__(256) void reduce2(const float* __restrict__ p0,
                                               const float* __restrict__ p1,
                                               const float* __restrict__ resid,
                                               const float* __restrict__ bias,
                                               float* __restrict__ out, int N)
{
    size_t idx = ((size_t)blockIdx.x * 256 + threadIdx.x) * 4;
    float4 a = *(const float4*)(p0 + idx);
    float4 b = *(const float4*)(p1 + idx);
    float4 r = *(const float4*)(resid + idx);
    float4 v;
    v.x = a.x + b.x + r.x; v.y = a.y + b.y + r.y;
    v.z = a.z + b.z + r.z; v.w = a.w + b.w + r.w;
    if constexpr (BIAS) {
        const float4 bv = *(const float4*)(bias + (idx & (N - 1)));
        v.x += bv.x; v.y += bv.y; v.z += bv.z; v.w += bv.w;
    }
    *(float4*)(out + idx) = v;
}

// ---------------------------------------------------------------------------
// Flash attention (causal), R5 "transposed-score" structure.
//   Grid (32,16,2), qt = 31-blockIdx.x (longest first), 64 Q rows per block
//   (4 waves x 16 rows).  Per 64-k tile:
//     S^T = K·Q^T via mfma_16x16x32 with SWAPPED operands (same fragments!):
//       lane holds S[q=l15][k = nt*16 + quad*4 + r] — one Q row per lane.
//     softmax: in-lane trees (16 vals) + shfl_xor(16/32) across quads.
//     P (bf16, perm-packed) is ALREADY in mfma_16x16x16bf16_1k A-layout:
//       PV accumulates straight from registers; V B-frags = b64 LDS reads.
//   Double-buffered K/V staging, ONE barrier/iter (R3 pattern).
// ---------------------------------------------------------------------------
__global__ __launch_bounds__(256) void attn_kernel(const short* __restrict__ qkv,
                                                   const short* __restrict__ vt,
                                                   short* __restrict__ out)
{
    __shared__ short Ks[2][64 * 64];
    __shared__ short Vs[2][64 * 64];
    const float CS = 0.125f * 1.44269504088896f;  // 1/sqrt(64) * log2(e)
    int tid  = threadIdx.x, lane = tid & 63, wv = tid >> 6;
    int quad = lane >> 4, l15 = lane & 15;
    int b = blockIdx.z, h = blockIdx.y;
    int qt = 31 - blockIdx.x;                     // longest blocks first
    int q0 = qt * 64;

    const size_t kbase = (size_t)b * 2048 * 3072 + 1024 + h * 64;
    const size_t vbase = (size_t)(b * 16 + h) * 64 * 2048;
    int srow = lane >> 3;                 // 0..7 : row within 8-row chunk
    int scol = ((lane & 7) ^ srow) * 8;   // XOR-swizzled store granule
    int rg0  = (quad ^ (l15 & 7)) * 8;    // swizzled b128 read offset

    // Q fragments (B-operand of the S^T MFMA — same load as the A-role)
    bf16x8 qf[2];
#pragma unroll
    for (int ks = 0; ks < 2; ++ks)
        qf[ks] = *(const bf16x8*)&qkv[(size_t)(b * 2048 + q0 + wv * 16 + l15) * 3072
                                       + h * 64 + ks * 32 + quad * 8];
    float mi = -3e38f, li = 0.0f;         // per-lane: Q row = l15 (quads dup)
    fx4 oacc[4] = {};

    // prologue: stage tile 0 into buffer 0
#pragma unroll
    for (int c = wv; c < 8; c += 4) {
        int row = c * 8 + srow;
        __builtin_amdgcn_global_load_lds(AS1(qkv + kbase + (size_t)row * 3072 + scol),
                                         AS3(&Ks[0][c * 512]), 16, 0, 0);
        __builtin_amdgcn_global_load_lds(AS1(vt + vbase + (size_t)row * 2048 + scol),
                                         AS3(&Vs[0][c * 512]), 16, 0, 0);
    }
    __syncthreads();

    for (int kt = 0; kt <= qt; ++kt) {
        int cur = kt & 1;
        if (kt < qt) {                    // stage next tile into alt buffer
            int nb = cur ^ 1, tn = (kt + 1) * 64;
#pragma unroll
            for (int c = wv; c < 8; c += 4) {
                int row = c * 8 + srow;
                __builtin_amdgcn_global_load_lds(AS1(qkv + kbase + (size_t)(tn + row) * 3072 + scol),
                                                 AS3(&Ks[nb][c * 512]), 16, 0, 0);
                __builtin_amdgcn_global_load_lds(AS1(vt + vbase + (size_t)row * 2048 + tn + scol),
                                                 AS3(&Vs[nb][c * 512]), 16, 0, 0);
            }
        }

        // S^T = K_tile · Q^T : lane holds S[q=l15][k = nt*16+quad*4+r]
        fx4 s[4];
#pragma unroll
        for (int nt = 0; nt < 4; ++nt) {
            bf16x8 kf0 = *(const bf16x8*)&Ks[cur][(nt * 16 + l15) * 64 + rg0];
            bf16x8 kf1 = *(const bf16x8*)&Ks[cur][(nt * 16 + l15) * 64 + (rg0 ^ 32)];
            fx4 z = {0.f, 0.f, 0.f, 0.f};
            z = __builtin_amdgcn_mfma_f32_16x16x32_bf16(kf0, qf[0], z, 0, 0, 0);
            z = __builtin_amdgcn_mfma_f32_16x16x32_bf16(kf1, qf[1], z, 0, 0, 0);
            s[nt] = z;
        }
        if (kt == qt) {                   // diagonal tile: causal mask
            int qrow = wv * 16 + l15;
#pragma unroll
            for (int nt = 0; nt < 4; ++nt)
#pragma unroll
                for (int r = 0; r < 4; ++r)
                    if (nt * 16 + quad * 4 + r > qrow) s[nt][r] = -3e38f;
        }

        // row max: in-lane tree over 16 + cross-quad xor16/xor32
        float m0_ = fmaxf(fmaxf(s[0][0], s[0][1]), fmaxf(s[0][2], s[0][3]));
        float m1_ = fmaxf(fmaxf(s[1][0], s[1][1]), fmaxf(s[1][2], s[1][3]));
        float m2_ = fmaxf(fmaxf(s[2][0], s[2][1]), fmaxf(s[2][2], s[2][3]));
        float m3_ = fmaxf(fmaxf(s[3][0], s[3][1]), fmaxf(s[3][2], s[3][3]));
        float vmax = fmaxf(fmaxf(m0_, m1_), fmaxf(m2_, m3_));
        vmax = fmaxf(vmax, __shfl_xor(vmax, 16));
        vmax = fmaxf(vmax, __shfl_xor(vmax, 32));
        float mnew  = fmaxf(mi, vmax);
        float alpha = exp2f((mi - mnew) * CS);
        float mc    = mnew * CS;
        mi = mnew;

        // p = exp2(s*CS - mc); pack to bf16 A-frags; accumulate row sum
        bf16x4 pf[4];
        float rs = 0.0f;
#pragma unroll
        for (int nt = 0; nt < 4; ++nt) {
            float p0 = exp2f(fmaf(s[nt][0], CS, -mc));
            float p1 = exp2f(fmaf(s[nt][1], CS, -mc));
            float p2 = exp2f(fmaf(s[nt][2], CS, -mc));
            float p3 = exp2f(fmaf(s[nt][3], CS, -mc));
            rs += (p0 + p1) + (p2 + p3);
            unsigned a0 = __builtin_bit_cast(unsigned, p0) + 0x8000u;
            unsigned a1 = __builtin_bit_cast(unsigned, p1) + 0x8000u;
            unsigned a2 = __builtin_bit_cast(unsigned, p2) + 0x8000u;
            unsigned a3 = __builtin_bit_cast(unsigned, p3) + 0x8000u;
            ix2 pk;
            pk[0] = (int)__builtin_amdgcn_perm(a1, a0, 0x07060302u);
            pk[1] = (int)__builtin_amdgcn_perm(a3, a2, 0x07060302u);
            pf[nt] = __builtin_bit_cast(bf16x4, pk);
        }
        rs += __shfl_xor(rs, 16);
        rs += __shfl_xor(rs, 32);
        li = li * alpha + rs;

        // scale O by alpha of its own rows (q = quad*4+r)
        float arow[4];
#pragma unroll
        for (int r = 0; r < 4; ++r) arow[r] = __shfl(alpha, quad * 4 + r, 16);
#pragma unroll
        for (int dt = 0; dt < 4; ++dt)
#pragma unroll
            for (int r = 0; r < 4; ++r) oacc[dt][r] *= arow[r];

        // PV: O[q][d] += P·V with K=16 MFMAs; B-frag = V[t=nt*16+quad*4+j][d]
#pragma unroll
        for (int dt = 0; dt < 4; ++dt) {
            int vrow  = dt * 16 + l15;
            int rbase = vrow * 64 + (quad & 1) * 4;
            int rk    = vrow & 7;
#pragma unroll
            for (int nt = 0; nt < 4; ++nt) {
                int g = (nt * 2 + (quad >> 1)) ^ rk;
                bf16x4 vf = *(const bf16x4*)&Vs[cur][rbase + g * 8];
                oacc[dt] = __builtin_amdgcn_mfma_f32_16x16x16bf16_1k(pf[nt], vf, oacc[dt], 0, 0, 0);
            }
        }
        __syncthreads();   // completes reads of buf[cur] + drains next loads
    }

    float linv[4];
#pragma unroll
    for (int r = 0; r < 4; ++r) linv[r] = 1.0f / __shfl(li, quad * 4 + r, 16);
#pragma unroll
    for (int dt = 0; dt < 4; ++dt)
#pragma unroll
        for (int r = 0; r < 4; ++r) {
            int row = q0 + wv * 16 + quad * 4 + r;
            int col = h * 64 + dt * 16 + l15;
            out[((size_t)b * 2048 + row) * 1024 + col] = f2bf(oacc[dt][r] * linv[r]);
        }
}

// ---------------------------------------------------------------------------
extern "C" void kernel_launch(void* const* d_in, const int* in_sizes, int n_in,
                              void* d_out, int out_size, void* d_ws, size_t ws_size,
                              hipStream_t stream)
{
    const float* x      = (const float*)d_in[0];
    const float* w_qkv  = (const float*)d_in[1];
    const float* w_proj = (const float*)d_in[2];
    const float* ln1_w  = (const float*)d_in[3];
    const float* ln1_b  = (const float*)d_in[4];
    const float* ln2_w  = (const float*)d_in[5];
    const float* ln2_b  = (const float*)d_in[6];
    const float* fc1_w  = (const float*)d_in[7];
    const float* fc1_b  = (const float*)d_in[8];
    const float* fc2_w  = (const float*)d_in[9];
    const float* fc2_b  = (const float*)d_in[10];
    float* out = (float*)d_out;
    char*  ws  = (char*)d_ws;

    size_t off = 0;
    auto alloc = [&](size_t bytes) { void* p = ws + off; off += (bytes + 255) & ~(size_t)255; return p; };
    short* tw_qkv  = (short*)alloc((size_t)3072 * 1024 * 2);
    short* tw_proj = (short*)alloc((size_t)1024 * 1024 * 2);
    short* tfc1    = (short*)alloc((size_t)4096 * 1024 * 2);
    short* tfc2    = (short*)alloc((size_t)1024 * 4096 * 2);
    short* xn      = (short*)alloc((size_t)4096 * 1024 * 2);
    short* qkvb    = (short*)alloc((size_t)4096 * 3072 * 2);
    short* vtb     = (short*)alloc((size_t)32 * 64 * 2048 * 2);
    short* attnb   = (short*)alloc((size_t)4096 * 1024 * 2);
    float* x1      = (float*)alloc((size_t)4096 * 1024 * 4);
    float* pk      = (float*)alloc((size_t)4096 * 1024 * 4);  // split-K slot 1
    short* h1      = qkvb;  // alias: qkv+vt dead after attention; h1 = 33.55MB

    dim3 tb(32, 8);
    transpose_f32_bf16<<<dim3(3072 / 32, 1024 / 32), tb, 0, stream>>>(w_qkv, tw_qkv, 1024, 3072);
    transpose_f32_bf16<<<dim3(1024 / 32, 1024 / 32), tb, 0, stream>>>(w_proj, tw_proj, 1024, 1024);
    transpose_f32_bf16<<<dim3(4096 / 32, 1024 / 32), tb, 0, stream>>>(fc1_w, tfc1, 1024, 4096);
    transpose_f32_bf16<<<dim3(1024 / 32, 4096 / 32), tb, 0, stream>>>(fc2_w, tfc2, 4096, 1024);

    ln_kernel<<<4096, 256, 0, stream>>>(x, ln1_w, ln1_b, xn);
    gemm_bt<128, false, false, false, true, false><<<dim3(24, 32, 1), 256, 0, stream>>>(
        xn, tw_qkv, qkvb, nullptr, nullptr, nullptr, 4096, 3072, 1024);
    vt_extract<<<dim3(2048 / 32, 64 / 32, 32), tb, 0, stream>>>(qkvb, vtb);
    attn_kernel<<<dim3(32, 16, 2), 256, 0, stream>>>(qkvb, vtb, attnb);
    gemm_bt<64, false, false, false, false, true><<<dim3(16, 32, 2), 256, 0, stream>>>(
        attnb, tw_proj, x1, pk, nullptr, nullptr, 4096, 1024, 1024);
    reduce2<false><<<4096, 256, 0, stream>>>(x1, pk, x, nullptr, x1, 1024);
    ln_kernel<<<4096, 256, 0, stream>>>(x1, ln2_w, ln2_b, xn);
    gemm_bt<128, true, true, false, true, false><<<dim3(32, 32, 1), 256, 0, stream>>>(
        xn, tfc1, h1, nullptr, fc1_b, nullptr, 4096, 4096, 1024);
    gemm_bt<64, false, false, false, false, true><<<dim3(16, 32, 2), 256, 0, stream>>>(
        h1, tfc2, out, pk, nullptr, nullptr, 4096, 1024, 4096);
    reduce2<true><<<4096, 256, 0, stream>>>(out, pk, x1, fc2_b, out, 1024);
}